// Round 7
// baseline (292.026 us; speedup 1.0000x reference)
//
#include <hip/hip_runtime.h>
#include <math.h>

#define NNB   576          // sequence length N
#define BNR   4608         // B*N rows
#define KSEL  51           // top-k along D

typedef unsigned short u16;
typedef __attribute__((ext_vector_type(8))) short bf16x8;
typedef __attribute__((ext_vector_type(4))) float f32x4;

// round-to-nearest (ties up) f32 -> bf16; inputs are finite
__device__ __forceinline__ u16 f2bf(float f) {
    unsigned u = __float_as_uint(f);
    return (u16)((u + 0x8000u) >> 16);
}
__device__ __forceinline__ unsigned pack2(float a, float b) {
    unsigned ua = __float_as_uint(a), ub = __float_as_uint(b);
    return ((ua + 0x8000u) >> 16) | ((ub + 0x8000u) & 0xffff0000u);
}
// async global->LDS DMA, 16B per lane; LDS dst = base + lane*16 (wave-uniform base)
__device__ __forceinline__ void load_lds16(const void* gp, void* lp) {
    __builtin_amdgcn_global_load_lds((const __attribute__((address_space(1))) void*)gp,
                                     (__attribute__((address_space(3))) void*)lp, 16, 0, 0);
}
// full-wave64 reductions via DPP (row_shr 1/2/4/8, bcast15, bcast31); uniform result
__device__ __forceinline__ float dpp_red_add_f(float x) {
    x += __int_as_float(__builtin_amdgcn_update_dpp(0, __float_as_int(x), 0x111, 0xf, 0xf, true));
    x += __int_as_float(__builtin_amdgcn_update_dpp(0, __float_as_int(x), 0x112, 0xf, 0xf, true));
    x += __int_as_float(__builtin_amdgcn_update_dpp(0, __float_as_int(x), 0x114, 0xf, 0xf, true));
    x += __int_as_float(__builtin_amdgcn_update_dpp(0, __float_as_int(x), 0x118, 0xf, 0xf, true));
    x += __int_as_float(__builtin_amdgcn_update_dpp(0, __float_as_int(x), 0x142, 0xa, 0xf, true));
    x += __int_as_float(__builtin_amdgcn_update_dpp(0, __float_as_int(x), 0x143, 0xc, 0xf, true));
    return __int_as_float(__builtin_amdgcn_readlane(__float_as_int(x), 63));
}
__device__ __forceinline__ unsigned dpp_red_max_u(unsigned x) {
    unsigned o;
    o = (unsigned)__builtin_amdgcn_update_dpp(0, (int)x, 0x111, 0xf, 0xf, true); x = x > o ? x : o;
    o = (unsigned)__builtin_amdgcn_update_dpp(0, (int)x, 0x112, 0xf, 0xf, true); x = x > o ? x : o;
    o = (unsigned)__builtin_amdgcn_update_dpp(0, (int)x, 0x114, 0xf, 0xf, true); x = x > o ? x : o;
    o = (unsigned)__builtin_amdgcn_update_dpp(0, (int)x, 0x118, 0xf, 0xf, true); x = x > o ? x : o;
    o = (unsigned)__builtin_amdgcn_update_dpp(0, (int)x, 0x142, 0xa, 0xf, true); x = x > o ? x : o;
    o = (unsigned)__builtin_amdgcn_update_dpp(0, (int)x, 0x143, 0xc, 0xf, true); x = x > o ? x : o;
    return (unsigned)__builtin_amdgcn_readlane((int)x, 63);
}

// ---------------------------------------------------------------------------
// qkv GEMM: C = A @ Bw^T + bias, A/Bw are f32, staged with inline bf16 pack.
// 64x128 tile, BK=64, 4 waves. Cols<512 (q) prescaled by log2(e)/8.
// Output bf16. Grid (12, 72) = 864 blocks.
// ---------------------------------------------------------------------------
__global__ __launch_bounds__(256)
void gemm_qkv(const float* __restrict__ A, const float* __restrict__ Bw,
              const float* __restrict__ bias, u16* __restrict__ Cv,
              int Nc, int Kd)
{
    __shared__ uint4 As4[512];    // 8 KB
    __shared__ uint4 Bs4[1024];   // 16 KB
    const int tid = threadIdx.x;
    const int lane = tid & 63, w = tid >> 6;
    const int r16 = lane & 15, quad = lane >> 4;
    const int r0 = blockIdx.y << 6, c0 = blockIdx.x << 7;

    const float* pA[2]; const float* pB[4];
    #pragma unroll
    for (int rd = 0; rd < 2; ++rd) {
        const int c = (rd << 8) + tid;            // chunk 0..511
        const int kb = c >> 8, g = (c >> 6) & 3, rr = (c >> 2) & 15, q = c & 3;
        pA[rd] = A + (size_t)(r0 + (g << 4) + rr) * Kd + (kb << 5) + (q << 3);
    }
    #pragma unroll
    for (int rd = 0; rd < 4; ++rd) {
        const int c = (rd << 8) + tid;            // chunk 0..1023
        const int kb = c >> 9, g = (c >> 6) & 7, rr = (c >> 2) & 15, q = c & 3;
        pB[rd] = Bw + (size_t)(c0 + (g << 4) + rr) * Kd + (kb << 5) + (q << 3);
    }

    f32x4 acc[4][2];
    #pragma unroll
    for (int i = 0; i < 4; ++i)
        #pragma unroll
        for (int j = 0; j < 2; ++j) acc[i][j] = (f32x4){0.f, 0.f, 0.f, 0.f};

    for (int kk = 0; kk < Kd; kk += 64) {
        float4 a0[2], a1[2], b0[4], b1[4];
        #pragma unroll
        for (int rd = 0; rd < 2; ++rd) {
            a0[rd] = *(const float4*)(pA[rd] + kk);
            a1[rd] = *(const float4*)(pA[rd] + kk + 4);
        }
        #pragma unroll
        for (int rd = 0; rd < 4; ++rd) {
            b0[rd] = *(const float4*)(pB[rd] + kk);
            b1[rd] = *(const float4*)(pB[rd] + kk + 4);
        }
        __syncthreads();   // previous iter's readers done
        #pragma unroll
        for (int rd = 0; rd < 2; ++rd) {
            uint4 pk;
            pk.x = pack2(a0[rd].x, a0[rd].y); pk.y = pack2(a0[rd].z, a0[rd].w);
            pk.z = pack2(a1[rd].x, a1[rd].y); pk.w = pack2(a1[rd].z, a1[rd].w);
            As4[(rd << 8) + tid] = pk;
        }
        #pragma unroll
        for (int rd = 0; rd < 4; ++rd) {
            uint4 pk;
            pk.x = pack2(b0[rd].x, b0[rd].y); pk.y = pack2(b0[rd].z, b0[rd].w);
            pk.z = pack2(b1[rd].x, b1[rd].y); pk.w = pack2(b1[rd].z, b1[rd].w);
            Bs4[(rd << 8) + tid] = pk;
        }
        __syncthreads();
        #pragma unroll
        for (int kb = 0; kb < 2; ++kb) {
            bf16x8 af[4], bfr[2];
            #pragma unroll
            for (int i = 0; i < 4; ++i)
                af[i] = *(const bf16x8*)&As4[((kb * 4 + i) << 6) + (r16 << 2) + quad];
            #pragma unroll
            for (int j = 0; j < 2; ++j)
                bfr[j] = *(const bf16x8*)&Bs4[((kb * 8 + (w << 1) + j) << 6) + (r16 << 2) + quad];
            #pragma unroll
            for (int i = 0; i < 4; ++i)
                #pragma unroll
                for (int j = 0; j < 2; ++j)
                    acc[i][j] = __builtin_amdgcn_mfma_f32_16x16x32_bf16(af[i], bfr[j], acc[i][j], 0, 0, 0);
        }
    }

    float bcol[2], scl[2];
    #pragma unroll
    for (int j = 0; j < 2; ++j) {
        const int col = c0 + (w << 5) + (j << 4) + r16;
        bcol[j] = bias[col];
        scl[j] = (col < 512) ? 0.180336880111120426f : 1.0f;  // log2(e)/8 on q cols
    }
    #pragma unroll
    for (int i = 0; i < 4; ++i) {
        #pragma unroll
        for (int reg = 0; reg < 4; ++reg) {
            const int row = r0 + (i << 4) + (quad << 2) + reg;
            const size_t base = (size_t)row * Nc;
            #pragma unroll
            for (int j = 0; j < 2; ++j) {
                const int col = c0 + (w << 5) + (j << 4) + r16;
                Cv[base + col] = f2bf((acc[i][j][reg] + bcol[j]) * scl[j]);
            }
        }
    }
}

// ---------------------------------------------------------------------------
// 64x64-tile GEMM: A bf16 (DMA-staged), Bw f32 (inline bf16 pack).
// C = A @ Bw^T + bias (+res). 576 blocks for the Nc=512 GEMMs.
// ---------------------------------------------------------------------------
template<bool RESID, bool OUT_BF16>
__global__ __launch_bounds__(256)
void gemm_6464(const u16* __restrict__ A, const float* __restrict__ Bw,
               const float* __restrict__ bias, const float* __restrict__ res,
               void* __restrict__ Cv, int Nc, int Kd)
{
    __shared__ uint4 As4[512];
    __shared__ uint4 Bs4[512];
    const int tid = threadIdx.x;
    const int lane = tid & 63, w = tid >> 6;
    const int wu = __builtin_amdgcn_readfirstlane(w);
    const int r16 = lane & 15, quad = lane >> 4;
    const int wy = w >> 1, wx = w & 1;
    const int r0 = blockIdx.y << 6, c0 = blockIdx.x << 6;

    const u16* pA[2]; const float* pB[2];
    #pragma unroll
    for (int rd = 0; rd < 2; ++rd) {
        const int c = (rd << 8) + tid;            // 0..511
        const int kb = c >> 8, g = (c >> 6) & 3, rr = (c >> 2) & 15, q = c & 3;
        const int row = (g << 4) + rr;
        const int koff = (kb << 5) + (q << 3);
        pA[rd] = A  + (size_t)(r0 + row) * Kd + koff;
        pB[rd] = Bw + (size_t)(c0 + row) * Kd + koff;
    }

    f32x4 acc[2][2];
    #pragma unroll
    for (int i = 0; i < 2; ++i)
        #pragma unroll
        for (int j = 0; j < 2; ++j) acc[i][j] = (f32x4){0.f, 0.f, 0.f, 0.f};

    for (int kk = 0; kk < Kd; kk += 64) {
        float4 b0[2], b1[2];
        #pragma unroll
        for (int rd = 0; rd < 2; ++rd) {
            b0[rd] = *(const float4*)(pB[rd] + kk);
            b1[rd] = *(const float4*)(pB[rd] + kk + 4);
        }
        __syncthreads();
        #pragma unroll
        for (int rd = 0; rd < 2; ++rd)
            load_lds16(pA[rd] + kk, (void*)(As4 + (rd << 8) + (wu << 6)));
        #pragma unroll
        for (int rd = 0; rd < 2; ++rd) {
            uint4 pk;
            pk.x = pack2(b0[rd].x, b0[rd].y); pk.y = pack2(b0[rd].z, b0[rd].w);
            pk.z = pack2(b1[rd].x, b1[rd].y); pk.w = pack2(b1[rd].z, b1[rd].w);
            Bs4[(rd << 8) + tid] = pk;
        }
        __syncthreads();
        #pragma unroll
        for (int kb = 0; kb < 2; ++kb) {
            bf16x8 af[2], bfr[2];
            #pragma unroll
            for (int i = 0; i < 2; ++i)
                af[i] = *(const bf16x8*)&As4[((kb * 4 + (wy << 1) + i) << 6) + (r16 << 2) + quad];
            #pragma unroll
            for (int j = 0; j < 2; ++j)
                bfr[j] = *(const bf16x8*)&Bs4[((kb * 4 + (wx << 1) + j) << 6) + (r16 << 2) + quad];
            #pragma unroll
            for (int i = 0; i < 2; ++i)
                #pragma unroll
                for (int j = 0; j < 2; ++j)
                    acc[i][j] = __builtin_amdgcn_mfma_f32_16x16x32_bf16(af[i], bfr[j], acc[i][j], 0, 0, 0);
        }
    }

    float bcol[2];
    #pragma unroll
    for (int j = 0; j < 2; ++j) bcol[j] = bias[c0 + (wx << 5) + (j << 4) + r16];
    #pragma unroll
    for (int i = 0; i < 2; ++i) {
        #pragma unroll
        for (int reg = 0; reg < 4; ++reg) {
            const int row = r0 + (wy << 5) + (i << 4) + (quad << 2) + reg;
            const size_t base = (size_t)row * Nc;
            #pragma unroll
            for (int j = 0; j < 2; ++j) {
                const int col = c0 + (wx << 5) + (j << 4) + r16;
                float v = acc[i][j][reg] + bcol[j];
                if (RESID) v += res[base + col];
                if (OUT_BF16) ((u16*)Cv)[base + col] = f2bf(v);
                else          ((float*)Cv)[base + col] = v;
            }
        }
    }
}

// ---------------------------------------------------------------------------
// bf16 MFMA flash attention, no-max softmax (q prescaled by log2e/8 -> exp2).
// Grid (64, 9): blockIdx.x = b*8+h so all 9 q-tiles of one (b,h) map to the
// same XCD (index % 8 invariant) -> K/V cached once per XCD.
// ---------------------------------------------------------------------------
__global__ __launch_bounds__(256)
void attn_mfma(const u16* __restrict__ qkv, u16* __restrict__ obuf)
{
    __shared__ uint4 Qf[512];
    __shared__ uint4 Kf[512];
    __shared__ u16  Vfs[4096];
    __shared__ u16  Pfs[4096];
    const int tid = threadIdx.x;
    const int lane = tid & 63, w = tid >> 6;
    const int wu = __builtin_amdgcn_readfirstlane(w);
    const int r16 = lane & 15, quad = lane >> 4;
    const int b = blockIdx.x >> 3, h = blockIdx.x & 7;
    const int i0 = blockIdx.y << 6;
    const u16* qb = qkv + (size_t)b * NNB * 1536 + h * 64;

    #pragma unroll
    for (int s = 0; s < 2; ++s) {        // stage Q once
        const int linear = (s << 8) + tid;
        const int r = linear >> 3, q7 = linear & 7;
        uint4 v = *(const uint4*)(qb + (size_t)(i0 + r) * 1536 + (q7 << 3));
        Qf[(((q7 >> 2) * 4 + (r >> 4)) << 6) + ((r & 15) << 2) + (q7 & 3)] = v;
    }
    const u16* pK[2];
    #pragma unroll
    for (int rd = 0; rd < 2; ++rd) {
        const int c = (rd << 8) + tid;
        const int kb = c >> 8, g = (c >> 6) & 3, rr = (c >> 2) & 15, q = c & 3;
        pK[rd] = qb + 512 + (size_t)((g << 4) + rr) * 1536 + (kb << 5) + (q << 3);
    }
    const int vp = tid >> 3, vq7 = tid & 7;     // V pair id / d-slice
    const int vj = vp << 1;
    const int vjl2 = (vj & 7) >> 1, vjq = (vj >> 3) & 3, vjkb = vj >> 5;

    float l_i[4] = {0.f, 0.f, 0.f, 0.f};
    f32x4 accO[4];
    #pragma unroll
    for (int f = 0; f < 4; ++f) accO[f] = (f32x4){0.f, 0.f, 0.f, 0.f};

    for (int j0 = 0; j0 < NNB; j0 += 64) {
        const u16* vbase = qb + 1024 + (size_t)(j0 + vj) * 1536 + (vq7 << 3);
        uint4 vA = *(const uint4*)vbase;
        uint4 vB = *(const uint4*)(vbase + 1536);
        __syncthreads();                 // previous iter's readers done
        load_lds16(pK[0] + (size_t)j0 * 1536, (void*)(Kf + (wu << 6)));
        load_lds16(pK[1] + (size_t)j0 * 1536, (void*)(Kf + 256 + (wu << 6)));
        {
            const u16* ea = (const u16*)&vA;
            const u16* eb = (const u16*)&vB;
            unsigned* V32 = (unsigned*)Vfs;
            #pragma unroll
            for (int e = 0; e < 8; ++e) {
                const int d = (vq7 << 3) + e;
                const int g = d >> 4;
                const int ch = ((vjkb * 4 + g) << 6) + ((((d & 15) << 2) + vjq) ^ g);
                V32[(ch << 2) + vjl2] = (unsigned)ea[e] | ((unsigned)eb[e] << 16);
            }
        }
        __syncthreads();

        f32x4 accS[4];
        #pragma unroll
        for (int f = 0; f < 4; ++f) accS[f] = (f32x4){0.f, 0.f, 0.f, 0.f};
        #pragma unroll
        for (int kb = 0; kb < 2; ++kb) {
            bf16x8 aq = *(const bf16x8*)&Qf[((kb * 4 + w) << 6) + (r16 << 2) + quad];
            #pragma unroll
            for (int f = 0; f < 4; ++f) {
                bf16x8 bk = *(const bf16x8*)&Kf[((kb * 4 + f) << 6) + (r16 << 2) + quad];
                accS[f] = __builtin_amdgcn_mfma_f32_16x16x32_bf16(aq, bk, accS[f], 0, 0, 0);
            }
        }
        #pragma unroll
        for (int reg = 0; reg < 4; ++reg) {
            const float s0 = exp2f(accS[0][reg]);
            const float s1 = exp2f(accS[1][reg]);
            const float s2 = exp2f(accS[2][reg]);
            const float s3 = exp2f(accS[3][reg]);
            l_i[reg] += (s0 + s1) + (s2 + s3);
            const int m = (quad << 2) + reg;
            const int sm = ((m & 3) << 2) + (m >> 2);     // digit-permuted m
            const float pv[4] = {s0, s1, s2, s3};
            #pragma unroll
            for (int f = 0; f < 4; ++f) {
                const int k = (f << 4) + r16;
                const int ch = (((k >> 5) * 4 + w) << 6) + (((k >> 3) & 3) << 4) + sm;
                Pfs[(ch << 3) + (k & 7)] = f2bf(pv[f]);
            }
        }
        #pragma unroll
        for (int kb = 0; kb < 2; ++kb) {
            bf16x8 ap = *(const bf16x8*)&Pfs[((((kb * 4 + w) << 6) + (quad << 4) + ((r16 & 3) << 2) + (r16 >> 2)) << 3)];
            #pragma unroll
            for (int f = 0; f < 4; ++f) {
                bf16x8 bv = *(const bf16x8*)&Vfs[((((kb * 4 + f) << 6) + (((r16 << 2) + quad) ^ f)) << 3)];
                accO[f] = __builtin_amdgcn_mfma_f32_16x16x32_bf16(ap, bv, accO[f], 0, 0, 0);
            }
        }
    }
    #pragma unroll
    for (int reg = 0; reg < 4; ++reg) {
        float l = l_i[reg];
        l += __shfl_xor(l, 1); l += __shfl_xor(l, 2);
        l += __shfl_xor(l, 4); l += __shfl_xor(l, 8);
        const float inv = 1.0f / l;
        const size_t row = (size_t)(b * NNB + i0 + (w << 4) + (quad << 2) + reg);
        #pragma unroll
        for (int f = 0; f < 4; ++f)
            obuf[row * 512 + (h << 6) + (f << 4) + r16] = f2bf(accO[f][reg] * inv);
    }
}

// ---------------------------------------------------------------------------
// Fused: LN+GELU -> comp -> exact top-51: phase A = max-exponent DESCEND
// (expected ~4 ballot rounds), then compacted distinct-key bisection with
// early exit; per-wave direct write of its 4 m-columns (bit-exact values).
// ---------------------------------------------------------------------------
__global__ __launch_bounds__(256)
void outer_topk(const float* __restrict__ F, const float* __restrict__ hraw,
                const float* __restrict__ lng, const float* __restrict__ lnb,
                const float* __restrict__ w2, const float* __restrict__ b2,
                const float* __restrict__ T, float* __restrict__ out)
{
    const int bn = blockIdx.x;
    const int tid = threadIdx.x;
    const int lane = tid & 63, w = tid >> 6;
    __shared__ float Fr[512];
    __shared__ float Hr[512];
    __shared__ unsigned keyslots[4][4][64];
    __shared__ float redsm[8];

    // --- load F row + raw h row; LN + exact GELU into Hr ---
    if (tid < 128)
        *(float4*)&Fr[tid << 2] = *(const float4*)(F + (size_t)bn * 512 + (tid << 2));
    const float* hp = hraw + (size_t)bn * 512;
    float x0 = hp[tid], x1 = hp[tid + 256];
    float sw = dpp_red_add_f(x0 + x1);
    float sqw = dpp_red_add_f(x0 * x0 + x1 * x1);
    if (lane == 0) { redsm[w] = sw; redsm[4 + w] = sqw; }
    __syncthreads();
    const float s  = redsm[0] + redsm[1] + redsm[2] + redsm[3];
    const float sq = redsm[4] + redsm[5] + redsm[6] + redsm[7];
    const float mean = s * (1.0f / 512.0f);
    const float var  = sq * (1.0f / 512.0f) - mean * mean;
    const float rstd = rsqrtf(var + 1e-5f);
    float y = (x0 - mean) * rstd * lng[tid] + lnb[tid];
    Hr[tid] = 0.5f * y * (1.0f + erff(y * 0.70710678118654752f));
    y = (x1 - mean) * rstd * lng[tid + 256] + lnb[tid + 256];
    Hr[tid + 256] = 0.5f * y * (1.0f + erff(y * 0.70710678118654752f));
    __syncthreads();

    // --- comp[m] = Hr . w2[m] + b2[m]; DPP reduce, uniform in all lanes ---
    const int m0 = w << 2;
    float cm[4];
    #pragma unroll
    for (int mi = 0; mi < 4; ++mi) {
        const float* w2p = w2 + (size_t)(m0 + mi) * 512;
        float p = 0.f;
        #pragma unroll
        for (int t = 0; t < 8; ++t) p += Hr[lane + (t << 6)] * w2p[lane + (t << 6)];
        cm[mi] = dpp_red_add_f(p) + b2[m0 + mi];
    }

    // --- abs bit patterns + sign mask (exact fp32 op order of reference) ---
    unsigned u[4][8]; unsigned smask[4];
    #pragma unroll
    for (int mi = 0; mi < 4; ++mi) {
        smask[mi] = 0u;
        const float* Tp = T + (size_t)(m0 + mi) * 512;
        #pragma unroll
        for (int t = 0; t < 8; ++t) {
            float pp = Fr[lane + (t << 6)] * Tp[lane + (t << 6)];
            float pc = pp * cm[mi];
            const unsigned bits = __float_as_uint(pc);
            u[mi][t] = bits & 0x7fffffffu;
            smask[mi] |= (bits >> 31) << t;
        }
    }

    // --- phase A: max-exponent descend (count >= cand per octave) ---
    unsigned pref[4], cand[4];
    int cntP[4], U[4];
    bool ad[4];
    #pragma unroll
    for (int mi = 0; mi < 4; ++mi) {
        unsigned mx = u[mi][0];
        #pragma unroll
        for (int t = 1; t < 8; ++t) mx = mx > u[mi][t] ? mx : u[mi][t];
        cand[mi] = dpp_red_max_u(mx) & 0xff800000u;   // E0 << 23
        pref[mi] = 0u; cntP[mi] = 512; U[mi] = 0; ad[mi] = false;
    }
    while (!(ad[0] & ad[1] & ad[2] & ad[3])) {
        #pragma unroll
        for (int mi = 0; mi < 4; ++mi) {
            if (ad[mi]) continue;
            int cnt = 0;
            #pragma unroll
            for (int t = 0; t < 8; ++t) cnt += __popcll(__ballot(u[mi][t] >= cand[mi]));
            if (cnt >= KSEL) { pref[mi] = cand[mi]; cntP[mi] = cnt; ad[mi] = true; }
            else             { U[mi] = cnt; cand[mi] -= (1u << 23); }
        }
    }
    // rare: extend bisection into mantissa until tie bucket fits in 64 slots
    int blo[4];
    #pragma unroll
    for (int mi = 0; mi < 4; ++mi) {
        int b = 23;
        while ((cntP[mi] - U[mi]) > 64 && b > 0) {
            --b;
            const unsigned cc2 = pref[mi] | (1u << b);
            int cnt = 0;
            #pragma unroll
            for (int t = 0; t < 8; ++t) cnt += __popcll(__ballot(u[mi][t] >= cc2));
            if (cnt >= KSEL) { pref[mi] = cc2; cntP[mi] = cnt; } else U[mi] = cnt;
        }
        blo[mi] = b;
    }
    int need[4]; bool done[4];
    #pragma unroll
    for (int mi = 0; mi < 4; ++mi) {
        need[mi] = KSEL - U[mi];
        done[mi] = (need[mi] == cntP[mi] - U[mi]);   // whole bucket selected
    }

    // --- compact tie bucket into distinct 32-bit keys, one slot per lane ---
    const unsigned long long lmask = (1ull << lane) - 1ull;
    unsigned kv[4] = {0u, 0u, 0u, 0u};
    #pragma unroll
    for (int mi = 0; mi < 4; ++mi) {
        if (done[mi]) continue;
        keyslots[w][mi][lane] = 0u;
        const int bl = blo[mi];
        const unsigned lowmask = (1u << bl) - 1u;
        int running = 0;
        #pragma unroll
        for (int t = 0; t < 8; ++t) {
            const bool tie = ((u[mi][t] ^ pref[mi]) >> bl) == 0u;
            const unsigned long long M = __ballot(tie);
            const int slot = running + __popcll(M & lmask);
            if (tie && slot < 64) {
                const unsigned key = ((u[mi][t] & lowmask) << 9) | (unsigned)(511 - ((t << 6) + lane));
                keyslots[w][mi][slot] = key;
            }
            running += __popcll(M);
        }
        kv[mi] = keyslots[w][mi][lane];
    }

    // --- phase B: bisect keys, 1 ballot/round, early exit on exact count ---
    unsigned prefk[4] = {0u, 0u, 0u, 0u};
    for (int bb = 31; bb >= 0; --bb) {
        if (done[0] & done[1] & done[2] & done[3]) break;
        #pragma unroll
        for (int mi = 0; mi < 4; ++mi) {
            if (done[mi]) continue;
            const unsigned candk = prefk[mi] | (1u << bb);
            const int c = __popcll(__ballot(kv[mi] >= candk));
            if (c >= need[mi]) {
                prefk[mi] = candk;
                if (c == need[mi]) done[mi] = true;
            }
        }
    }

    // --- per-wave direct write of its 4 m-columns (bit-exact values) ---
    float* ob = out + (size_t)bn * 8192 + m0;
    #pragma unroll
    for (int t = 0; t < 8; ++t) {
        const int d = (t << 6) + lane;
        float4 v;
        float* vv = &v.x;
        #pragma unroll
        for (int mi = 0; mi < 4; ++mi) {
            const unsigned uu = u[mi][t];
            const int bl = blo[mi];
            const bool tie = ((uu ^ pref[mi]) >> bl) == 0u;
            const unsigned key = ((uu & ((1u << bl) - 1u)) << 9) | (unsigned)(511 - d);
            const bool sel = (uu >= pref[mi] + (1u << bl)) || (tie && key >= prefk[mi]);
            const unsigned bits = uu | (((smask[mi] >> t) & 1u) << 31);
            vv[mi] = sel ? __uint_as_float(bits) : 0.0f;
        }
        *(float4*)(ob + (size_t)d * 16) = v;
    }
}

// ---------------------------------------------------------------------------
extern "C" void kernel_launch(void* const* d_in, const int* in_sizes, int n_in,
                              void* d_out, int out_size, void* d_ws, size_t ws_size,
                              hipStream_t stream)
{
    const float* F    = (const float*)d_in[0];
    const float* ipw  = (const float*)d_in[1];
    const float* ipb  = (const float*)d_in[2];
    const float* opw  = (const float*)d_in[3];
    const float* opb  = (const float*)d_in[4];
    const float* w1   = (const float*)d_in[5];
    const float* b1   = (const float*)d_in[6];
    const float* lng  = (const float*)d_in[7];
    const float* lnb  = (const float*)d_in[8];
    const float* w2   = (const float*)d_in[9];
    const float* b2   = (const float*)d_in[10];
    const float* tmpl = (const float*)d_in[11];

    char* wsb = (char*)d_ws;
    u16*   qkvb  = (u16*)wsb;                     // 4608*1536 bf16 = 14155776 B
    u16*   obufb = (u16*)(wsb + 14155776);        // 4608*512 bf16
    u16*   fenhb = (u16*)(wsb + 18874368);        // 4608*512 bf16
    float* hbuf  = (float*)(wsb + 23592960);      // 4608*512 f32 (raw, pre-LN)

    // qkv = F @ ipw^T + ipb (q cols prescaled by log2e/8), inline f32->bf16
    gemm_qkv<<<dim3(12, 72), 256, 0, stream>>>(F, ipw, ipb, qkvb, 1536, 512);
    // o = attention(qkv); grid (bh, i0) keeps each (b,h)'s KV on one XCD
    attn_mfma<<<dim3(64, 9), 256, 0, stream>>>(qkvb, obufb);
    // F_enh = o @ opw^T + opb + F -> bf16 (A via DMA, B inline f32->bf16)
    gemm_6464<true, true><<<dim3(8, 72), 256, 0, stream>>>(obufb, opw, opb, F, fenhb, 512, 512);
    // h_raw = F_enh @ w1^T + b1 -> fp32
    gemm_6464<false, false><<<dim3(8, 72), 256, 0, stream>>>(fenhb, w1, b1, nullptr, hbuf, 512, 512);
    // LN+GELU + comp + exact top-51 + direct sparse write (fused)
    outer_topk<<<4608, 256, 0, stream>>>(F, hbuf, lng, lnb, w2, b2, tmpl, (float*)d_out);
}